// Round 12
// baseline (192.344 us; speedup 1.0000x reference)
//
#include <hip/hip_runtime.h>
#include <hip/hip_bf16.h>
#include <math.h>

#define B_ 4
#define S_ 2048
#define H_ 512
#define HEADS_ 8
#define DK_ 64
#define NROWS_ (B_*S_)          // 8192
#define LN_EPS_ 1e-5f
#define NEG_INF_ -1e30f
// Q pre-scale: 1/sqrt(DK) * log2(e)  (softmax done in exp2 domain)
#define QSCALE_ (0.125f * 1.44269504088896f)

typedef short s8v __attribute__((ext_vector_type(8)));   // 8 bf16 (4 VGPRs)
typedef short s4v __attribute__((ext_vector_type(4)));   // 4 bf16 (2 VGPRs)
typedef float f4v __attribute__((ext_vector_type(4)));

typedef __attribute__((address_space(1))) unsigned int gu32_t;
typedef __attribute__((address_space(3))) unsigned int lu32_t;

__device__ __forceinline__ unsigned short f2bf(float f) {
    unsigned int u = __float_as_uint(f);
    u += 0x7FFFu + ((u >> 16) & 1u);     // round-to-nearest-even
    return (unsigned short)(u >> 16);
}

__device__ __forceinline__ float bf2f(unsigned short u) {
    return __uint_as_float((unsigned int)u << 16);
}

__device__ __forceinline__ s4v pk4bf(float a, float b, float c, float d) {
    union { __hip_bfloat162 h[2]; s4v v; } u;
    u.h[0] = __float22bfloat162_rn(float2{a, b});
    u.h[1] = __float22bfloat162_rn(float2{c, d});
    return u.v;
}

// ---------------------------------------------------------------------------
// Kernel 1: PREP = LayerNorm (blocks 0..2047) + weight transpose (2048..3071).
// LN: wave-per-row, float4 loads, emits bf16 xnb + mask-bias mb.
// WT: Wt (2048x512 bf16): rows 0..511 Wq*QSCALE | Wk | Wv | Wo-cols.
// ---------------------------------------------------------------------------
__global__ __launch_bounds__(256) void prep_kernel(
        const float* __restrict__ x, const float* __restrict__ gamma,
        const float* __restrict__ beta, const int* __restrict__ mask,
        const float* __restrict__ Wq, const float* __restrict__ Wk,
        const float* __restrict__ Wv, const float* __restrict__ Wo,
        unsigned short* __restrict__ xnb, float* __restrict__ mb,
        unsigned short* __restrict__ Wt) {
    int bx = blockIdx.x;
    if (bx < 2048) {                       // ---------------- LayerNorm
        int row  = bx * 4 + (threadIdx.x >> 6);
        int lane = threadIdx.x & 63;
        const float4* xr = (const float4*)(x + (size_t)row * H_ + lane * 8);
        float4 a = xr[0], d = xr[1];
        float s  = (a.x + a.y) + (a.z + a.w) + (d.x + d.y) + (d.z + d.w);
        float ss = (a.x*a.x + a.y*a.y) + (a.z*a.z + a.w*a.w)
                 + (d.x*d.x + d.y*d.y) + (d.z*d.z + d.w*d.w);
        #pragma unroll
        for (int i = 1; i < 64; i <<= 1) {
            s  += __shfl_xor(s, i, 64);
            ss += __shfl_xor(ss, i, 64);
        }
        float mu  = s * (1.f / 512.f);
        float var = ss * (1.f / 512.f) - mu * mu;
        float rstd = rsqrtf(var + LN_EPS_);
        if (lane == 0) mb[row] = mask[row] ? 0.f : NEG_INF_;
        const float4* gp = (const float4*)(gamma + lane * 8);
        const float4* bp = (const float4*)(beta + lane * 8);
        float4 g0 = gp[0], g1 = gp[1], b0 = bp[0], b1 = bp[1];
        float4 y0, y1;
        y0.x = (a.x - mu) * rstd * g0.x + b0.x;
        y0.y = (a.y - mu) * rstd * g0.y + b0.y;
        y0.z = (a.z - mu) * rstd * g0.z + b0.z;
        y0.w = (a.w - mu) * rstd * g0.w + b0.w;
        y1.x = (d.x - mu) * rstd * g1.x + b1.x;
        y1.y = (d.y - mu) * rstd * g1.y + b1.y;
        y1.z = (d.z - mu) * rstd * g1.z + b1.z;
        y1.w = (d.w - mu) * rstd * g1.w + b1.w;
        union { s4v h[2]; s8v v; } pk;
        pk.h[0] = pk4bf(y0.x, y0.y, y0.z, y0.w);
        pk.h[1] = pk4bf(y1.x, y1.y, y1.z, y1.w);
        *(s8v*)(xnb + (size_t)row * H_ + lane * 8) = pk.v;
    } else {                               // ---------------- weight transpose
        __shared__ float tile[32][33];
        int wid = bx - 2048;
        const float* src;
        int ld, drow, k0, c0;
        float scale = 1.f;
        if (wid < 768) {
            int z = wid >> 5, rem = wid & 31;
            int cx = rem & 1, ky = rem >> 1;
            k0 = ky * 32; c0 = cx * 32;
            int zw = z >> 3, head = z & 7;
            const float* W = (zw == 0) ? Wq : (zw == 1) ? Wk : Wv;
            if (zw == 0) scale = QSCALE_;
            src = W + (size_t)head * H_ * DK_;
            ld = DK_;
            drow = zw * 512 + head * 64;
        } else {
            int rem = wid - 768;
            int cx = rem & 15, ky = rem >> 4;
            k0 = ky * 32; c0 = cx * 32;
            src = Wo; ld = H_; drow = 1536;
        }
        int tx = threadIdx.x & 31, ty = threadIdx.x >> 5;
        #pragma unroll
        for (int i = 0; i < 4; i++)
            tile[ty * 4 + i][tx] = src[(size_t)(k0 + ty * 4 + i) * ld + c0 + tx];
        __syncthreads();
        #pragma unroll
        for (int i = 0; i < 4; i++) {
            int cc = ty * 4 + i;
            Wt[(size_t)(drow + c0 + cc) * 512 + k0 + tx] = f2bf(tile[tx][cc] * scale);
        }
    }
}

// ---------------------------------------------------------------------------
// Shared MFMA GEMM tile loop. BK=64 per chunk as TWO m97-style [128][32]
// sub-stages (DMA-compatible layout, verified 64B ds_read stride), so the
// barrier+vmcnt drain count halves vs BK=32: 16 drains for 256 MFMAs.
// ---------------------------------------------------------------------------
__device__ __forceinline__ void gemm_tile(
        const unsigned short* __restrict__ A,
        const unsigned short* __restrict__ Bt,
        int r0, int j0, f4v acc[4][4]) {
    __shared__ unsigned short As[2 * 128 * 32];
    __shared__ unsigned short Bs[2 * 128 * 32];
    int t = threadIdx.x;
    int wv = t >> 6, L = t & 63, c = L & 15, g = L >> 4;
    int m_base = (wv & 1) * 64, n_base = (wv >> 1) * 64;
    #pragma unroll
    for (int i = 0; i < 4; i++)
        #pragma unroll
        for (int j = 0; j < 4; j++) acc[i][j] = (f4v){0.f, 0.f, 0.f, 0.f};
    for (int k0 = 0; k0 < 512; k0 += 64) {
        __syncthreads();                     // prior readers done
        #pragma unroll
        for (int half = 0; half < 2; half++) {
            #pragma unroll
            for (int i = 0; i < 2; i++) {
                int u = wv * 128 + i * 64 + L;   // 16B unit in this half
                int row = u >> 2, k16 = u & 3;
                __builtin_amdgcn_global_load_lds(
                    (const gu32_t*)(A + (size_t)(r0 + row) * 512 + k0 + half * 32 + k16 * 8),
                    (lu32_t*)(As + half * 4096 + (size_t)(wv * 128 + i * 64) * 8), 16, 0, 0);
                __builtin_amdgcn_global_load_lds(
                    (const gu32_t*)(Bt + (size_t)(j0 + row) * 512 + k0 + half * 32 + k16 * 8),
                    (lu32_t*)(Bs + half * 4096 + (size_t)(wv * 128 + i * 64) * 8), 16, 0, 0);
            }
        }
        __asm__ volatile("s_waitcnt vmcnt(0)" ::: "memory");
        __syncthreads();                     // staged data visible
        #pragma unroll
        for (int half = 0; half < 2; half++) {
            s8v a[4], b[4];
            #pragma unroll
            for (int i = 0; i < 4; i++)
                a[i] = *(const s8v*)(As + half * 4096 + (size_t)(m_base + i * 16 + c) * 32 + g * 8);
            #pragma unroll
            for (int j = 0; j < 4; j++)
                b[j] = *(const s8v*)(Bs + half * 4096 + (size_t)(n_base + j * 16 + c) * 32 + g * 8);
            #pragma unroll
            for (int i = 0; i < 4; i++)
                #pragma unroll
                for (int j = 0; j < 4; j++)
                    acc[i][j] = __builtin_amdgcn_mfma_f32_16x16x32_bf16(
                        a[i], b[j], acc[i][j], 0, 0, 0);
        }
    }
}

// ---------------------------------------------------------------------------
// Kernel 2: QKV GEMM (epilogues unchanged).
// ---------------------------------------------------------------------------
__global__ __launch_bounds__(256) void qkv_gemm(
        const unsigned short* __restrict__ xnb,
        const unsigned short* __restrict__ Wt,
        unsigned short* __restrict__ Qb, unsigned short* __restrict__ Kf,
        unsigned short* __restrict__ Vf) {
    f4v acc[4][4];
    int t = threadIdx.x;
    int wv = t >> 6, L = t & 63, c = L & 15, g = L >> 4;
    int rb = wv & 1, cb = wv >> 1;
    if (blockIdx.x < 8) {
        int m0 = blockIdx.x * 128, n0 = blockIdx.y * 128;
        gemm_tile(Wt, xnb, m0, n0, acc);
        int R0 = m0 + rb * 64;            // Wt-row base (64-aligned, one head)
        int C0 = n0 + cb * 64;            // token base (64-aligned)
        int hd = (R0 >> 6) & 7;
        int b  = C0 >> 11, srow0 = C0 & 2047;
        size_t bhbase = (size_t)(b * HEADS_ + hd) * S_ * DK_;
        if (R0 < 512) {                   // ---- Q: row-major (token, dk)
            #pragma unroll
            for (int msub = 0; msub < 4; msub++) {
                int dk4 = msub * 16 + g * 4;
                #pragma unroll
                for (int nsub = 0; nsub < 4; nsub++) {
                    int tok = srow0 + nsub * 16 + c;
                    s4v v = pk4bf(acc[msub][nsub][0], acc[msub][nsub][1],
                                  acc[msub][nsub][2], acc[msub][nsub][3]);
                    *(s4v*)(Qb + bhbase + (size_t)tok * DK_ + dk4) = v;
                }
            }
        } else {                          // ---- K: fragment-major
            unsigned short* dst = Kf + bhbase + (size_t)(srow0 >> 6) * 4096;
            #pragma unroll
            for (int msub = 0; msub < 4; msub++) {
                int gx = (msub & 1) * 2 + (g >> 1);
                int slotbase = (g & 1) * 4 + (msub >> 1) * 8;
                #pragma unroll
                for (int nsub = 0; nsub < 4; nsub++) {
                    s4v v = pk4bf(acc[msub][nsub][0], acc[msub][nsub][1],
                                  acc[msub][nsub][2], acc[msub][nsub][3]);
                    *(s4v*)(dst + nsub * 1024 + (gx * 16 + c) * 16 + slotbase) = v;
                }
            }
        }
    } else {
        int r0 = blockIdx.y * 128, j0 = 1024 + (blockIdx.x - 8) * 128;
        gemm_tile(xnb, Wt, r0, j0, acc);
        int R0 = r0 + rb * 64;            // token base
        int C0 = j0 + cb * 64;            // col base
        int hd = (C0 >> 6) & 7;
        int b = R0 >> 11, srow0 = R0 & 2047;
        unsigned short* dst = Vf + (size_t)(b * HEADS_ + hd) * S_ * DK_
                              + (size_t)(srow0 >> 6) * 4096;
        #pragma unroll
        for (int msub = 0; msub < 4; msub++)
            #pragma unroll
            for (int nsub = 0; nsub < 4; nsub++) {
                s4v v = pk4bf(acc[msub][nsub][0], acc[msub][nsub][1],
                              acc[msub][nsub][2], acc[msub][nsub][3]);
                *(s4v*)(dst + nsub * 1024 + (g * 16 + c) * 16 + msub * 4) = v;
            }
    }
}

// ---------------------------------------------------------------------------
// Kernel 3: flash attention (unchanged logic; launch_bounds (256,4) for
// 4 blocks/CU: need ~110 regs/thread < 128 budget).
// ---------------------------------------------------------------------------
__global__ __launch_bounds__(256, 4) void attn_kernel(
        const unsigned short* __restrict__ Qb,
        const unsigned short* __restrict__ Kf,
        const unsigned short* __restrict__ Vf,
        const float* __restrict__ mb,
        unsigned short* __restrict__ hb) {
    __shared__ float red[2][64][2][17];  // [qsub][lane][qgroup][16 acc + l]

    int wv   = threadIdx.x >> 6;
    int qsub = wv & 1;
    int kp   = wv >> 1;                  // keypart: 0 or 1
    int L  = threadIdx.x & 63;
    int c  = L & 15;            // q within 16-q tile
    int g  = L >> 4;            // quad
    int bh = blockIdx.y;
    int b  = bh >> 3, n = bh & 7;
    int q0 = blockIdx.x * 64 + qsub * 32;    // wave owns q0..q0+31

    const unsigned short* Qbase = Qb + (size_t)bh * S_ * DK_;
    const unsigned short* Kp = Kf + (size_t)bh * S_ * DK_ + (size_t)kp * 16 * 4096 + L * 16;
    const unsigned short* Vp = Vf + (size_t)bh * S_ * DK_ + (size_t)kp * 16 * 4096 + L * 16;
    const float* mbrow = mb + b * S_ + kp * 1024;

    s8v qfA0 = *(const s8v*)(Qbase + (size_t)(q0 + c) * DK_ + g * 8);
    s8v qfA1 = *(const s8v*)(Qbase + (size_t)(q0 + c) * DK_ + 32 + g * 8);
    s8v qfB0 = *(const s8v*)(Qbase + (size_t)(q0 + 16 + c) * DK_ + g * 8);
    s8v qfB1 = *(const s8v*)(Qbase + (size_t)(q0 + 16 + c) * DK_ + 32 + g * 8);

    f4v accA[4], accB[4];       // O^T: d = dsub*16 + g*4 + r
    #pragma unroll
    for (int i = 0; i < 4; i++) {
        accA[i] = (f4v){0.f, 0.f, 0.f, 0.f};
        accB[i] = (f4v){0.f, 0.f, 0.f, 0.f};
    }
    float lacA[4] = {0.f, 0.f, 0.f, 0.f};
    float lacB[4] = {0.f, 0.f, 0.f, 0.f};

    for (int kb = 0; kb < 16; kb++) {
        const unsigned short* Kn = Kp + (size_t)kb * 4096;
        const unsigned short* Vn = Vp + (size_t)kb * 4096;
        #pragma unroll
        for (int h = 0; h < 2; h++) {    // two 32-key halves
            // ---- VMEM for this half: 4 K + 2 bias + 4 V ----
            s8v k0lo = *(const s8v*)(Kn + (h * 2 + 0) * 1024);
            s8v k0hi = *(const s8v*)(Kn + (h * 2 + 0) * 1024 + 8);
            s8v k1lo = *(const s8v*)(Kn + (h * 2 + 1) * 1024);
            s8v k1hi = *(const s8v*)(Kn + (h * 2 + 1) * 1024 + 8);
            float4 mb0 = *(const float4*)(mbrow + kb * 64 + h * 32 + g * 4);
            float4 mb1 = *(const float4*)(mbrow + kb * 64 + h * 32 + 16 + g * 4);
            s8v vv[4];
            #pragma unroll
            for (int ds = 0; ds < 4; ds++)
                vv[ds] = *(const s8v*)(Vn + ds * 1024 + h * 8);
            // ---- S^T MFMAs, C initialized with the mask bias ----
            f4v bias0 = (f4v){mb0.x, mb0.y, mb0.z, mb0.w};
            f4v bias1 = (f4v){mb1.x, mb1.y, mb1.z, mb1.w};
            f4v sA0 = bias0, sA1 = bias1, sB0 = bias0, sB1 = bias1;
            sA0 = __builtin_amdgcn_mfma_f32_16x16x32_bf16(k0lo, qfA0, sA0, 0, 0, 0);
            sA0 = __builtin_amdgcn_mfma_f32_16x16x32_bf16(k0hi, qfA1, sA0, 0, 0, 0);
            sA1 = __builtin_amdgcn_mfma_f32_16x16x32_bf16(k1lo, qfA0, sA1, 0, 0, 0);
            sA1 = __builtin_amdgcn_mfma_f32_16x16x32_bf16(k1hi, qfA1, sA1, 0, 0, 0);
            sB0 = __builtin_amdgcn_mfma_f32_16x16x32_bf16(k0lo, qfB0, sB0, 0, 0, 0);
            sB0 = __builtin_amdgcn_mfma_f32_16x16x32_bf16(k0hi, qfB1, sB0, 0, 0, 0);
            sB1 = __builtin_amdgcn_mfma_f32_16x16x32_bf16(k1lo, qfB0, sB1, 0, 0, 0);
            sB1 = __builtin_amdgcn_mfma_f32_16x16x32_bf16(k1hi, qfB1, sB1, 0, 0, 0);
            // ---- exp2 + partial sums (mask already applied as bias) ----
            float pA0[4], pA1[4], pB0[4], pB1[4];
            #pragma unroll
            for (int r = 0; r < 4; r++) {
                pA0[r] = __builtin_amdgcn_exp2f(sA0[r]);
                pA1[r] = __builtin_amdgcn_exp2f(sA1[r]);
                pB0[r] = __builtin_amdgcn_exp2f(sB0[r]);
                pB1[r] = __builtin_amdgcn_exp2f(sB1[r]);
                lacA[r] += pA0[r] + pA1[r];
                lacB[r] += pB0[r] + pB1[r];
            }
            s4v pfA0 = pk4bf(pA0[0], pA0[1], pA0[2], pA0[3]);
            s4v pfA1 = pk4bf(pA1[0], pA1[1], pA1[2], pA1[3]);
            s4v pfB0 = pk4bf(pB0[0], pB0[1], pB0[2], pB0[3]);
            s4v pfB1 = pk4bf(pB1[0], pB1[1], pB1[2], pB1[3]);
            // ---- O^T += V^T . P^T ----
            #pragma unroll
            for (int ds = 0; ds < 4; ds++) {
                s4v v0 = __builtin_shufflevector(vv[ds], vv[ds], 0, 1, 2, 3);
                s4v v1 = __builtin_shufflevector(vv[ds], vv[ds], 4, 5, 6, 7);
                accA[ds] = __builtin_amdgcn_mfma_f32_16x16x16bf16_1k(v0, pfA0, accA[ds], 0, 0, 0);
                accA[ds] = __builtin_amdgcn_mfma_f32_16x16x16bf16_1k(v1, pfA1, accA[ds], 0, 0, 0);
                accB[ds] = __builtin_amdgcn_mfma_f32_16x16x16bf16_1k(v0, pfB0, accB[ds], 0, 0, 0);
                accB[ds] = __builtin_amdgcn_mfma_f32_16x16x16bf16_1k(v1, pfB1, accB[ds], 0, 0, 0);
            }
        }
    }

    float lA = (lacA[0] + lacA[1]) + (lacA[2] + lacA[3]);
    float lB = (lacB[0] + lacB[1]) + (lacB[2] + lacB[3]);
    lA += __shfl_xor(lA, 16, 64);
    lA += __shfl_xor(lA, 32, 64);
    lB += __shfl_xor(lB, 16, 64);
    lB += __shfl_xor(lB, 32, 64);

    // ---- combine keyparts through LDS ----
    if (kp == 1) {
        #pragma unroll
        for (int d = 0; d < 4; d++) {
            #pragma unroll
            for (int r = 0; r < 4; r++) {
                red[qsub][L][0][d * 4 + r] = accA[d][r];
                red[qsub][L][1][d * 4 + r] = accB[d][r];
            }
        }
        red[qsub][L][0][16] = lA;
        red[qsub][L][1][16] = lB;
    }
    __syncthreads();
    if (kp == 0) {
        const float* srcA = &red[qsub][L][0][0];
        const float* srcB = &red[qsub][L][1][0];
        float invA = 1.f / (lA + srcA[16]);
        float invB = 1.f / (lB + srcB[16]);
        unsigned short* hpA = hb + (size_t)(b * S_ + q0 + c) * H_ + n * DK_ + g * 4;
        unsigned short* hpB = hpA + (size_t)16 * H_;
        #pragma unroll
        for (int ds = 0; ds < 4; ds++) {
            s4v oA = pk4bf((accA[ds][0] + srcA[ds * 4 + 0]) * invA,
                           (accA[ds][1] + srcA[ds * 4 + 1]) * invA,
                           (accA[ds][2] + srcA[ds * 4 + 2]) * invA,
                           (accA[ds][3] + srcA[ds * 4 + 3]) * invA);
            *(s4v*)(hpA + ds * 16) = oA;
            s4v oB = pk4bf((accB[ds][0] + srcB[ds * 4 + 0]) * invB,
                           (accB[ds][1] + srcB[ds * 4 + 1]) * invB,
                           (accB[ds][2] + srcB[ds * 4 + 2]) * invB,
                           (accB[ds][3] + srcB[ds * 4 + 3]) * invB);
            *(s4v*)(hpB + ds * 16) = oB;
        }
    }
}

// ---------------------------------------------------------------------------
// Kernel 4: out = (hb @ Wot^T + xnb) * mask. Residual from bf16 xnb.
// ---------------------------------------------------------------------------
__global__ __launch_bounds__(256) void out_gemm(
        const unsigned short* __restrict__ hb,
        const unsigned short* __restrict__ Wot,
        const unsigned short* __restrict__ xnb, const int* __restrict__ mask,
        float* __restrict__ out) {
    f4v acc[4][4];
    int r0 = blockIdx.y * 128, j0 = blockIdx.x * 128;
    gemm_tile(hb, Wot, r0, j0, acc);
    int t = threadIdx.x;
    int wv = t >> 6, L = t & 63, c = L & 15, g = L >> 4;
    int mrow = r0 + (wv & 1) * 64 + g * 4;
    int ncol = j0 + (wv >> 1) * 64 + c;
    #pragma unroll
    for (int msub = 0; msub < 4; msub++) {
        #pragma unroll
        for (int rr = 0; rr < 4; rr++) {
            int row = mrow + msub * 16 + rr;
            float mf = (float)mask[row];
            #pragma unroll
            for (int nsub = 0; nsub < 4; nsub++) {
                int col = ncol + nsub * 16;
                size_t o = (size_t)row * H_ + col;
                out[o] = (acc[msub][nsub][rr] + bf2f(xnb[o])) * mf;
            }
        }
    }
}

// ---------------------------------------------------------------------------
extern "C" void kernel_launch(void* const* d_in, const int* in_sizes, int n_in,
                              void* d_out, int out_size, void* d_ws, size_t ws_size,
                              hipStream_t stream) {
    const float* x     = (const float*)d_in[0];
    const int*   mask  = (const int*)d_in[1];
    const float* Wq    = (const float*)d_in[2];
    const float* Wk    = (const float*)d_in[3];
    const float* Wv    = (const float*)d_in[4];
    const float* Wo    = (const float*)d_in[5];
    const float* gamma = (const float*)d_in[6];
    const float* beta  = (const float*)d_in[7];
    float* out = (float*)d_out;

    size_t nelem = (size_t)NROWS_ * H_;   // 4M elements
    char* ws = (char*)d_ws;
    unsigned short* xnb = (unsigned short*)ws; ws += nelem * 2;   // 8 MB
    unsigned short* hb  = (unsigned short*)ws; ws += nelem * 2;   // 8 MB
    unsigned short* Qb  = (unsigned short*)ws; ws += nelem * 2;   // 8 MB
    unsigned short* Kf  = (unsigned short*)ws; ws += nelem * 2;   // 8 MB
    unsigned short* Vf  = (unsigned short*)ws; ws += nelem * 2;   // 8 MB
    unsigned short* Wt  = (unsigned short*)ws; ws += (size_t)2048 * 512 * 2; // 2 MB
    float*          mbp = (float*)ws;                             // 32 KB

    prep_kernel<<<3072, 256, 0, stream>>>(
        x, gamma, beta, mask, Wq, Wk, Wv, Wo, xnb, mbp, Wt);
    qkv_gemm<<<dim3(12, 64), 256, 0, stream>>>(xnb, Wt, Qb, Kf, Vf);
    attn_kernel<<<dim3(S_ / 64, B_ * HEADS_), 256, 0, stream>>>(
        Qb, Kf, Vf, mbp, hb);
    out_gemm<<<dim3(4, 64), 256, 0, stream>>>(
        hb, Wt + (size_t)1536 * 512, xnb, mask, out);
}

// Round 13
// 179.187 us; speedup vs baseline: 1.0734x; 1.0734x over previous
//
#include <hip/hip_runtime.h>
#include <hip/hip_bf16.h>
#include <math.h>

#define B_ 4
#define S_ 2048
#define H_ 512
#define HEADS_ 8
#define DK_ 64
#define NROWS_ (B_*S_)          // 8192
#define LN_EPS_ 1e-5f
#define NEG_INF_ -1e30f
// Q pre-scale: 1/sqrt(DK) * log2(e)  (softmax done in exp2 domain)
#define QSCALE_ (0.125f * 1.44269504088896f)

typedef short s8v __attribute__((ext_vector_type(8)));   // 8 bf16 (4 VGPRs)
typedef short s4v __attribute__((ext_vector_type(4)));   // 4 bf16 (2 VGPRs)
typedef float f4v __attribute__((ext_vector_type(4)));

typedef __attribute__((address_space(1))) unsigned int gu32_t;
typedef __attribute__((address_space(3))) unsigned int lu32_t;

__device__ __forceinline__ unsigned short f2bf(float f) {
    unsigned int u = __float_as_uint(f);
    u += 0x7FFFu + ((u >> 16) & 1u);     // round-to-nearest-even
    return (unsigned short)(u >> 16);
}

__device__ __forceinline__ float bf2f(unsigned short u) {
    return __uint_as_float((unsigned int)u << 16);
}

__device__ __forceinline__ s4v pk4bf(float a, float b, float c, float d) {
    union { __hip_bfloat162 h[2]; s4v v; } u;
    u.h[0] = __float22bfloat162_rn(float2{a, b});
    u.h[1] = __float22bfloat162_rn(float2{c, d});
    return u.v;
}

// ---------------------------------------------------------------------------
// Kernel 1: PREP = LayerNorm (blocks 0..2047) + weight transpose (2048..3071).
// ---------------------------------------------------------------------------
__global__ __launch_bounds__(256) void prep_kernel(
        const float* __restrict__ x, const float* __restrict__ gamma,
        const float* __restrict__ beta, const int* __restrict__ mask,
        const float* __restrict__ Wq, const float* __restrict__ Wk,
        const float* __restrict__ Wv, const float* __restrict__ Wo,
        unsigned short* __restrict__ xnb, float* __restrict__ mb,
        unsigned short* __restrict__ Wt) {
    int bx = blockIdx.x;
    if (bx < 2048) {                       // ---------------- LayerNorm
        int row  = bx * 4 + (threadIdx.x >> 6);
        int lane = threadIdx.x & 63;
        const float4* xr = (const float4*)(x + (size_t)row * H_ + lane * 8);
        float4 a = xr[0], d = xr[1];
        float s  = (a.x + a.y) + (a.z + a.w) + (d.x + d.y) + (d.z + d.w);
        float ss = (a.x*a.x + a.y*a.y) + (a.z*a.z + a.w*a.w)
                 + (d.x*d.x + d.y*d.y) + (d.z*d.z + d.w*d.w);
        #pragma unroll
        for (int i = 1; i < 64; i <<= 1) {
            s  += __shfl_xor(s, i, 64);
            ss += __shfl_xor(ss, i, 64);
        }
        float mu  = s * (1.f / 512.f);
        float var = ss * (1.f / 512.f) - mu * mu;
        float rstd = rsqrtf(var + LN_EPS_);
        if (lane == 0) mb[row] = mask[row] ? 0.f : NEG_INF_;
        const float4* gp = (const float4*)(gamma + lane * 8);
        const float4* bp = (const float4*)(beta + lane * 8);
        float4 g0 = gp[0], g1 = gp[1], b0 = bp[0], b1 = bp[1];
        float4 y0, y1;
        y0.x = (a.x - mu) * rstd * g0.x + b0.x;
        y0.y = (a.y - mu) * rstd * g0.y + b0.y;
        y0.z = (a.z - mu) * rstd * g0.z + b0.z;
        y0.w = (a.w - mu) * rstd * g0.w + b0.w;
        y1.x = (d.x - mu) * rstd * g1.x + b1.x;
        y1.y = (d.y - mu) * rstd * g1.y + b1.y;
        y1.z = (d.z - mu) * rstd * g1.z + b1.z;
        y1.w = (d.w - mu) * rstd * g1.w + b1.w;
        union { s4v h[2]; s8v v; } pk;
        pk.h[0] = pk4bf(y0.x, y0.y, y0.z, y0.w);
        pk.h[1] = pk4bf(y1.x, y1.y, y1.z, y1.w);
        *(s8v*)(xnb + (size_t)row * H_ + lane * 8) = pk.v;
    } else {                               // ---------------- weight transpose
        __shared__ float tile[32][33];
        int wid = bx - 2048;
        const float* src;
        int ld, drow, k0, c0;
        float scale = 1.f;
        if (wid < 768) {
            int z = wid >> 5, rem = wid & 31;
            int cx = rem & 1, ky = rem >> 1;
            k0 = ky * 32; c0 = cx * 32;
            int zw = z >> 3, head = z & 7;
            const float* W = (zw == 0) ? Wq : (zw == 1) ? Wk : Wv;
            if (zw == 0) scale = QSCALE_;
            src = W + (size_t)head * H_ * DK_;
            ld = DK_;
            drow = zw * 512 + head * 64;
        } else {
            int rem = wid - 768;
            int cx = rem & 15, ky = rem >> 4;
            k0 = ky * 32; c0 = cx * 32;
            src = Wo; ld = H_; drow = 1536;
        }
        int tx = threadIdx.x & 31, ty = threadIdx.x >> 5;
        #pragma unroll
        for (int i = 0; i < 4; i++)
            tile[ty * 4 + i][tx] = src[(size_t)(k0 + ty * 4 + i) * ld + c0 + tx];
        __syncthreads();
        #pragma unroll
        for (int i = 0; i < 4; i++) {
            int cc = ty * 4 + i;
            Wt[(size_t)(drow + c0 + cc) * 512 + k0 + tx] = f2bf(tile[tx][cc] * scale);
        }
    }
}

// ---------------------------------------------------------------------------
// Shared MFMA GEMM tile loop. BK=64 per chunk as TWO m97-style [128][32]
// sub-stages: 16 barrier+vmcnt drains for 256 MFMAs.
// ---------------------------------------------------------------------------
__device__ __forceinline__ void gemm_tile(
        const unsigned short* __restrict__ A,
        const unsigned short* __restrict__ Bt,
        int r0, int j0, f4v acc[4][4]) {
    __shared__ unsigned short As[2 * 128 * 32];
    __shared__ unsigned short Bs[2 * 128 * 32];
    int t = threadIdx.x;
    int wv = t >> 6, L = t & 63, c = L & 15, g = L >> 4;
    int m_base = (wv & 1) * 64, n_base = (wv >> 1) * 64;
    #pragma unroll
    for (int i = 0; i < 4; i++)
        #pragma unroll
        for (int j = 0; j < 4; j++) acc[i][j] = (f4v){0.f, 0.f, 0.f, 0.f};
    for (int k0 = 0; k0 < 512; k0 += 64) {
        __syncthreads();                     // prior readers done
        #pragma unroll
        for (int half = 0; half < 2; half++) {
            #pragma unroll
            for (int i = 0; i < 2; i++) {
                int u = wv * 128 + i * 64 + L;   // 16B unit in this half
                int row = u >> 2, k16 = u & 3;
                __builtin_amdgcn_global_load_lds(
                    (const gu32_t*)(A + (size_t)(r0 + row) * 512 + k0 + half * 32 + k16 * 8),
                    (lu32_t*)(As + half * 4096 + (size_t)(wv * 128 + i * 64) * 8), 16, 0, 0);
                __builtin_amdgcn_global_load_lds(
                    (const gu32_t*)(Bt + (size_t)(j0 + row) * 512 + k0 + half * 32 + k16 * 8),
                    (lu32_t*)(Bs + half * 4096 + (size_t)(wv * 128 + i * 64) * 8), 16, 0, 0);
            }
        }
        __asm__ volatile("s_waitcnt vmcnt(0)" ::: "memory");
        __syncthreads();                     // staged data visible
        #pragma unroll
        for (int half = 0; half < 2; half++) {
            s8v a[4], b[4];
            #pragma unroll
            for (int i = 0; i < 4; i++)
                a[i] = *(const s8v*)(As + half * 4096 + (size_t)(m_base + i * 16 + c) * 32 + g * 8);
            #pragma unroll
            for (int j = 0; j < 4; j++)
                b[j] = *(const s8v*)(Bs + half * 4096 + (size_t)(n_base + j * 16 + c) * 32 + g * 8);
            #pragma unroll
            for (int i = 0; i < 4; i++)
                #pragma unroll
                for (int j = 0; j < 4; j++)
                    acc[i][j] = __builtin_amdgcn_mfma_f32_16x16x32_bf16(
                        a[i], b[j], acc[i][j], 0, 0, 0);
        }
    }
}

// ---------------------------------------------------------------------------
// Kernel 2: QKV GEMM (epilogues unchanged).
// ---------------------------------------------------------------------------
__global__ __launch_bounds__(256) void qkv_gemm(
        const unsigned short* __restrict__ xnb,
        const unsigned short* __restrict__ Wt,
        unsigned short* __restrict__ Qb, unsigned short* __restrict__ Kf,
        unsigned short* __restrict__ Vf) {
    f4v acc[4][4];
    int t = threadIdx.x;
    int wv = t >> 6, L = t & 63, c = L & 15, g = L >> 4;
    int rb = wv & 1, cb = wv >> 1;
    if (blockIdx.x < 8) {
        int m0 = blockIdx.x * 128, n0 = blockIdx.y * 128;
        gemm_tile(Wt, xnb, m0, n0, acc);
        int R0 = m0 + rb * 64;            // Wt-row base (64-aligned, one head)
        int C0 = n0 + cb * 64;            // token base (64-aligned)
        int hd = (R0 >> 6) & 7;
        int b  = C0 >> 11, srow0 = C0 & 2047;
        size_t bhbase = (size_t)(b * HEADS_ + hd) * S_ * DK_;
        if (R0 < 512) {                   // ---- Q: row-major (token, dk)
            #pragma unroll
            for (int msub = 0; msub < 4; msub++) {
                int dk4 = msub * 16 + g * 4;
                #pragma unroll
                for (int nsub = 0; nsub < 4; nsub++) {
                    int tok = srow0 + nsub * 16 + c;
                    s4v v = pk4bf(acc[msub][nsub][0], acc[msub][nsub][1],
                                  acc[msub][nsub][2], acc[msub][nsub][3]);
                    *(s4v*)(Qb + bhbase + (size_t)tok * DK_ + dk4) = v;
                }
            }
        } else {                          // ---- K: fragment-major
            unsigned short* dst = Kf + bhbase + (size_t)(srow0 >> 6) * 4096;
            #pragma unroll
            for (int msub = 0; msub < 4; msub++) {
                int gx = (msub & 1) * 2 + (g >> 1);
                int slotbase = (g & 1) * 4 + (msub >> 1) * 8;
                #pragma unroll
                for (int nsub = 0; nsub < 4; nsub++) {
                    s4v v = pk4bf(acc[msub][nsub][0], acc[msub][nsub][1],
                                  acc[msub][nsub][2], acc[msub][nsub][3]);
                    *(s4v*)(dst + nsub * 1024 + (gx * 16 + c) * 16 + slotbase) = v;
                }
            }
        }
    } else {
        int r0 = blockIdx.y * 128, j0 = 1024 + (blockIdx.x - 8) * 128;
        gemm_tile(xnb, Wt, r0, j0, acc);
        int R0 = r0 + rb * 64;            // token base
        int C0 = j0 + cb * 64;            // col base
        int hd = (C0 >> 6) & 7;
        int b = R0 >> 11, srow0 = R0 & 2047;
        unsigned short* dst = Vf + (size_t)(b * HEADS_ + hd) * S_ * DK_
                              + (size_t)(srow0 >> 6) * 4096;
        #pragma unroll
        for (int msub = 0; msub < 4; msub++)
            #pragma unroll
            for (int nsub = 0; nsub < 4; nsub++) {
                s4v v = pk4bf(acc[msub][nsub][0], acc[msub][nsub][1],
                              acc[msub][nsub][2], acc[msub][nsub][3]);
                *(s4v*)(dst + nsub * 1024 + (g * 16 + c) * 16 + msub * 4) = v;
            }
    }
}

// ---------------------------------------------------------------------------
// Kernel 3: flash attention. launch_bounds (256,3): the proven no-spill
// config (round 11: 67us, VGPR 76, WRITE 8MB). (256,4) spilled (round 12:
// +11MB scratch, 80us) and (512,8)/(512,4) both lost — ~150 total regs is
// this kernel's sweet spot; do not squeeze below it.
// ---------------------------------------------------------------------------
__global__ __launch_bounds__(256, 3) void attn_kernel(
        const unsigned short* __restrict__ Qb,
        const unsigned short* __restrict__ Kf,
        const unsigned short* __restrict__ Vf,
        const float* __restrict__ mb,
        unsigned short* __restrict__ hb) {
    __shared__ float red[2][64][2][17];  // [qsub][lane][qgroup][16 acc + l]

    int wv   = threadIdx.x >> 6;
    int qsub = wv & 1;
    int kp   = wv >> 1;                  // keypart: 0 or 1
    int L  = threadIdx.x & 63;
    int c  = L & 15;            // q within 16-q tile
    int g  = L >> 4;            // quad
    int bh = blockIdx.y;
    int b  = bh >> 3, n = bh & 7;
    int q0 = blockIdx.x * 64 + qsub * 32;    // wave owns q0..q0+31

    const unsigned short* Qbase = Qb + (size_t)bh * S_ * DK_;
    const unsigned short* Kp = Kf + (size_t)bh * S_ * DK_ + (size_t)kp * 16 * 4096 + L * 16;
    const unsigned short* Vp = Vf + (size_t)bh * S_ * DK_ + (size_t)kp * 16 * 4096 + L * 16;
    const float* mbrow = mb + b * S_ + kp * 1024;

    s8v qfA0 = *(const s8v*)(Qbase + (size_t)(q0 + c) * DK_ + g * 8);
    s8v qfA1 = *(const s8v*)(Qbase + (size_t)(q0 + c) * DK_ + 32 + g * 8);
    s8v qfB0 = *(const s8v*)(Qbase + (size_t)(q0 + 16 + c) * DK_ + g * 8);
    s8v qfB1 = *(const s8v*)(Qbase + (size_t)(q0 + 16 + c) * DK_ + 32 + g * 8);

    f4v accA[4], accB[4];       // O^T: d = dsub*16 + g*4 + r
    #pragma unroll
    for (int i = 0; i < 4; i++) {
        accA[i] = (f4v){0.f, 0.f, 0.f, 0.f};
        accB[i] = (f4v){0.f, 0.f, 0.f, 0.f};
    }
    float lacA[4] = {0.f, 0.f, 0.f, 0.f};
    float lacB[4] = {0.f, 0.f, 0.f, 0.f};

    for (int kb = 0; kb < 16; kb++) {
        const unsigned short* Kn = Kp + (size_t)kb * 4096;
        const unsigned short* Vn = Vp + (size_t)kb * 4096;
        #pragma unroll
        for (int h = 0; h < 2; h++) {    // two 32-key halves
            // ---- VMEM for this half: 4 K + 2 bias + 4 V ----
            s8v k0lo = *(const s8v*)(Kn + (h * 2 + 0) * 1024);
            s8v k0hi = *(const s8v*)(Kn + (h * 2 + 0) * 1024 + 8);
            s8v k1lo = *(const s8v*)(Kn + (h * 2 + 1) * 1024);
            s8v k1hi = *(const s8v*)(Kn + (h * 2 + 1) * 1024 + 8);
            float4 mb0 = *(const float4*)(mbrow + kb * 64 + h * 32 + g * 4);
            float4 mb1 = *(const float4*)(mbrow + kb * 64 + h * 32 + 16 + g * 4);
            s8v vv[4];
            #pragma unroll
            for (int ds = 0; ds < 4; ds++)
                vv[ds] = *(const s8v*)(Vn + ds * 1024 + h * 8);
            // ---- S^T MFMAs, C initialized with the mask bias ----
            f4v bias0 = (f4v){mb0.x, mb0.y, mb0.z, mb0.w};
            f4v bias1 = (f4v){mb1.x, mb1.y, mb1.z, mb1.w};
            f4v sA0 = bias0, sA1 = bias1, sB0 = bias0, sB1 = bias1;
            sA0 = __builtin_amdgcn_mfma_f32_16x16x32_bf16(k0lo, qfA0, sA0, 0, 0, 0);
            sA0 = __builtin_amdgcn_mfma_f32_16x16x32_bf16(k0hi, qfA1, sA0, 0, 0, 0);
            sA1 = __builtin_amdgcn_mfma_f32_16x16x32_bf16(k1lo, qfA0, sA1, 0, 0, 0);
            sA1 = __builtin_amdgcn_mfma_f32_16x16x32_bf16(k1hi, qfA1, sA1, 0, 0, 0);
            sB0 = __builtin_amdgcn_mfma_f32_16x16x32_bf16(k0lo, qfB0, sB0, 0, 0, 0);
            sB0 = __builtin_amdgcn_mfma_f32_16x16x32_bf16(k0hi, qfB1, sB0, 0, 0, 0);
            sB1 = __builtin_amdgcn_mfma_f32_16x16x32_bf16(k1lo, qfB0, sB1, 0, 0, 0);
            sB1 = __builtin_amdgcn_mfma_f32_16x16x32_bf16(k1hi, qfB1, sB1, 0, 0, 0);
            // ---- exp2 + partial sums (mask already applied as bias) ----
            float pA0[4], pA1[4], pB0[4], pB1[4];
            #pragma unroll
            for (int r = 0; r < 4; r++) {
                pA0[r] = __builtin_amdgcn_exp2f(sA0[r]);
                pA1[r] = __builtin_amdgcn_exp2f(sA1[r]);
                pB0[r] = __builtin_amdgcn_exp2f(sB0[r]);
                pB1[r] = __builtin_amdgcn_exp2f(sB1[r]);
                lacA[r] += pA0[r] + pA1[r];
                lacB[r] += pB0[r] + pB1[r];
            }
            s4v pfA0 = pk4bf(pA0[0], pA0[1], pA0[2], pA0[3]);
            s4v pfA1 = pk4bf(pA1[0], pA1[1], pA1[2], pA1[3]);
            s4v pfB0 = pk4bf(pB0[0], pB0[1], pB0[2], pB0[3]);
            s4v pfB1 = pk4bf(pB1[0], pB1[1], pB1[2], pB1[3]);
            // ---- O^T += V^T . P^T ----
            #pragma unroll
            for (int ds = 0; ds < 4; ds++) {
                s4v v0 = __builtin_shufflevector(vv[ds], vv[ds], 0, 1, 2, 3);
                s4v v1 = __builtin_shufflevector(vv[ds], vv[ds], 4, 5, 6, 7);
                accA[ds] = __builtin_amdgcn_mfma_f32_16x16x16bf16_1k(v0, pfA0, accA[ds], 0, 0, 0);
                accA[ds] = __builtin_amdgcn_mfma_f32_16x16x16bf16_1k(v1, pfA1, accA[ds], 0, 0, 0);
                accB[ds] = __builtin_amdgcn_mfma_f32_16x16x16bf16_1k(v0, pfB0, accB[ds], 0, 0, 0);
                accB[ds] = __builtin_amdgcn_mfma_f32_16x16x16bf16_1k(v1, pfB1, accB[ds], 0, 0, 0);
            }
        }
    }

    float lA = (lacA[0] + lacA[1]) + (lacA[2] + lacA[3]);
    float lB = (lacB[0] + lacB[1]) + (lacB[2] + lacB[3]);
    lA += __shfl_xor(lA, 16, 64);
    lA += __shfl_xor(lA, 32, 64);
    lB += __shfl_xor(lB, 16, 64);
    lB += __shfl_xor(lB, 32, 64);

    // ---- combine keyparts through LDS ----
    if (kp == 1) {
        #pragma unroll
        for (int d = 0; d < 4; d++) {
            #pragma unroll
            for (int r = 0; r < 4; r++) {
                red[qsub][L][0][d * 4 + r] = accA[d][r];
                red[qsub][L][1][d * 4 + r] = accB[d][r];
            }
        }
        red[qsub][L][0][16] = lA;
        red[qsub][L][1][16] = lB;
    }
    __syncthreads();
    if (kp == 0) {
        const float* srcA = &red[qsub][L][0][0];
        const float* srcB = &red[qsub][L][1][0];
        float invA = 1.f / (lA + srcA[16]);
        float invB = 1.f / (lB + srcB[16]);
        unsigned short* hpA = hb + (size_t)(b * S_ + q0 + c) * H_ + n * DK_ + g * 4;
        unsigned short* hpB = hpA + (size_t)16 * H_;
        #pragma unroll
        for (int ds = 0; ds < 4; ds++) {
            s4v oA = pk4bf((accA[ds][0] + srcA[ds * 4 + 0]) * invA,
                           (accA[ds][1] + srcA[ds * 4 + 1]) * invA,
                           (accA[ds][2] + srcA[ds * 4 + 2]) * invA,
                           (accA[ds][3] + srcA[ds * 4 + 3]) * invA);
            *(s4v*)(hpA + ds * 16) = oA;
            s4v oB = pk4bf((accB[ds][0] + srcB[ds * 4 + 0]) * invB,
                           (accB[ds][1] + srcB[ds * 4 + 1]) * invB,
                           (accB[ds][2] + srcB[ds * 4 + 2]) * invB,
                           (accB[ds][3] + srcB[ds * 4 + 3]) * invB);
            *(s4v*)(hpB + ds * 16) = oB;
        }
    }
}

// ---------------------------------------------------------------------------
// Kernel 4: out = (hb @ Wot^T + xnb) * mask. Residual from bf16 xnb.
// ---------------------------------------------------------------------------
__global__ __launch_bounds__(256) void out_gemm(
        const unsigned short* __restrict__ hb,
        const unsigned short* __restrict__ Wot,
        const unsigned short* __restrict__ xnb, const int* __restrict__ mask,
        float* __restrict__ out) {
    f4v acc[4][4];
    int r0 = blockIdx.y * 128, j0 = blockIdx.x * 128;
    gemm_tile(hb, Wot, r0, j0, acc);
    int t = threadIdx.x;
    int wv = t >> 6, L = t & 63, c = L & 15, g = L >> 4;
    int mrow = r0 + (wv & 1) * 64 + g * 4;
    int ncol = j0 + (wv >> 1) * 64 + c;
    #pragma unroll
    for (int msub = 0; msub < 4; msub++) {
        #pragma unroll
        for (int rr = 0; rr < 4; rr++) {
            int row = mrow + msub * 16 + rr;
            float mf = (float)mask[row];
            #pragma unroll
            for (int nsub = 0; nsub < 4; nsub++) {
                int col = ncol + nsub * 16;
                size_t o = (size_t)row * H_ + col;
                out[o] = (acc[msub][nsub][rr] + bf2f(xnb[o])) * mf;
            }
        }
    }
}

// ---------------------------------------------------------------------------
extern "C" void kernel_launch(void* const* d_in, const int* in_sizes, int n_in,
                              void* d_out, int out_size, void* d_ws, size_t ws_size,
                              hipStream_t stream) {
    const float* x     = (const float*)d_in[0];
    const int*   mask  = (const int*)d_in[1];
    const float* Wq    = (const float*)d_in[2];
    const float* Wk    = (const float*)d_in[3];
    const float* Wv    = (const float*)d_in[4];
    const float* Wo    = (const float*)d_in[5];
    const float* gamma = (const float*)d_in[6];
    const float* beta  = (const float*)d_in[7];
    float* out = (float*)d_out;

    size_t nelem = (size_t)NROWS_ * H_;   // 4M elements
    char* ws = (char*)d_ws;
    unsigned short* xnb = (unsigned short*)ws; ws += nelem * 2;   // 8 MB
    unsigned short* hb  = (unsigned short*)ws; ws += nelem * 2;   // 8 MB
    unsigned short* Qb  = (unsigned short*)ws; ws += nelem * 2;   // 8 MB
    unsigned short* Kf  = (unsigned short*)ws; ws += nelem * 2;   // 8 MB
    unsigned short* Vf  = (unsigned short*)ws; ws += nelem * 2;   // 8 MB
    unsigned short* Wt  = (unsigned short*)ws; ws += (size_t)2048 * 512 * 2; // 2 MB
    float*          mbp = (float*)ws;                             // 32 KB

    prep_kernel<<<3072, 256, 0, stream>>>(
        x, gamma, beta, mask, Wq, Wk, Wv, Wo, xnb, mbp, Wt);
    qkv_gemm<<<dim3(12, 64), 256, 0, stream>>>(xnb, Wt, Qb, Kf, Vf);
    attn_kernel<<<dim3(S_ / 64, B_ * HEADS_), 256, 0, stream>>>(
        Qb, Kf, Vf, mbp, hb);
    out_gemm<<<dim3(4, 64), 256, 0, stream>>>(
        hb, Wt + (size_t)1536 * 512, xnb, mask, out);
}